// Round 1
// baseline (175.844 us; speedup 1.0000x reference)
//
#include <hip/hip_runtime.h>

typedef unsigned short u16;
typedef __attribute__((ext_vector_type(8))) short bf16x8;
typedef __attribute__((ext_vector_type(4))) float f32x4;

__device__ __forceinline__ u16 f2bf(float f) {
    union { float f; unsigned u; } v; v.f = f;
    unsigned r = (v.u + 0x7FFFu + ((v.u >> 16) & 1u)) >> 16;
    return (u16)r;
}

// ---------------- setup kernel 1: edge softmax into ws (padded 32x32 grid) ---
__global__ void edge_softmax_k(const float* __restrict__ rg,
                               const float* __restrict__ gb,
                               float* __restrict__ ew) {
    int tid = blockIdx.x * 256 + threadIdx.x;      // 0..1023 = i*32+j
    if (tid >= 1024) return;
    int i = tid >> 5, j = tid & 31;
    float w0 = 0.f, w1 = 0.f;
    if (i != j) {
        int e = i * 31 + j - (j > i ? 1 : 0);      // original edge index
        float a0 = (rg[e * 2 + 0] + gb[e * 2 + 0]) * 2.0f;   // /TAU, TAU=0.5
        float a1 = (rg[e * 2 + 1] + gb[e * 2 + 1]) * 2.0f;
        float m = fmaxf(a0, a1);
        float e0 = expf(a0 - m), e1 = expf(a1 - m);
        float s = e0 + e1;
        w0 = e0 / s; w1 = e1 / s;
    }
    ew[tid * 2 + 0] = w0;
    ew[tid * 2 + 1] = w1;
}

// ---------------- setup kernel 2: pack weights into MFMA B-fragment order ----
// B-frag (16x16x32): lane l supplies B[32*s + 8*(l>>4) + j][16*t + (l&15)], j=0..7
__global__ void pack_weights_k(const float* __restrict__ W1,   // (2,32,64)
                               const float* __restrict__ W2,   // (2,64,64)
                               const float* __restrict__ OW1,  // (80,64)
                               const float* __restrict__ OW2,  // (64,64)
                               const float* __restrict__ OW3,  // (64,16)
                               u16* __restrict__ wp) {
    int tid = blockIdx.x * 256 + threadIdx.x;
    if (tid < 4096) {                                     // w1p [k][t][lane][8]
        int j = tid & 7, l = (tid >> 3) & 63, t = (tid >> 9) & 3, k = tid >> 11;
        int kk = 8 * (l >> 4) + j, n = 16 * t + (l & 15);
        wp[tid] = f2bf(W1[k * 2048 + kk * 64 + n]);
    } else if (tid < 12288) {                             // w2p [k][s][t][lane][8]
        int x = tid - 4096;
        int j = x & 7, l = (x >> 3) & 63, t = (x >> 9) & 3, s = (x >> 11) & 1, k = x >> 12;
        int kk = 32 * s + 8 * (l >> 4) + j, n = 16 * t + (l & 15);
        wp[tid] = f2bf(W2[k * 4096 + kk * 64 + n]);
    } else if (tid < 18432) {                             // ow1p [s3][t][lane][8], K=80 zero-padded to 96
        int x = tid - 12288;
        int j = x & 7, l = (x >> 3) & 63, t = (x >> 9) & 3, s = x >> 11;
        int kk = 32 * s + 8 * (l >> 4) + j, n = 16 * t + (l & 15);
        wp[tid] = f2bf(kk < 80 ? OW1[kk * 64 + n] : 0.f);
    } else if (tid < 22528) {                             // ow2p [s2][t][lane][8]
        int x = tid - 18432;
        int j = x & 7, l = (x >> 3) & 63, t = (x >> 9) & 3, s = x >> 11;
        int kk = 32 * s + 8 * (l >> 4) + j, n = 16 * t + (l & 15);
        wp[tid] = f2bf(OW2[kk * 64 + n]);
    } else if (tid < 23552) {                             // ow3p [s2][lane][8], N=16
        int x = tid - 22528;
        int j = x & 7, l = (x >> 3) & 63, s = x >> 9;
        int kk = 32 * s + 8 * (l >> 4) + j, n = (l & 15);
        wp[tid] = f2bf(OW3[kk * 16 + n]);
    }
}

// ---------------- main fused kernel: one block per (b, tp) -------------------
__global__ __launch_bounds__(256, 2) void nri_decoder_k(
    const float* __restrict__ inputs,   // (32,32,64,16)
    const float* __restrict__ mb1, const float* __restrict__ mb2,
    const float* __restrict__ ob1, const float* __restrict__ ob2,
    const float* __restrict__ ob3,
    const float* __restrict__ ew,       // (1024,2) padded edge weights
    const u16*  __restrict__ wp,        // packed weights
    float* __restrict__ out)            // (32,32,63,16)
{
    __shared__ float xsf[32][16];
    __shared__ __align__(16) u16 xsb[32][24];     // 48B rows (pad: bank spread)
    __shared__ float agg[32][64];
    __shared__ __align__(16) u16 slab[4][16][72]; // per-wave h1, 144B rows
    __shared__ __align__(16) u16 augb[32][104];   // 208B rows, cols 80-95 zero
    __shared__ __align__(16) u16 p1b[32][72];
    __shared__ __align__(16) u16 p2b[32][72];

    const int tid = threadIdx.x;
    const int w = tid >> 6, lane = tid & 63, g = lane >> 4, lr = lane & 15;
    const int b = blockIdx.x >> 5, tp = blockIdx.x & 31;

    const u16* w1p  = wp;
    const u16* w2p  = wp + 4096;
    const u16* ow1p = wp + 12288;
    const u16* ow2p = wp + 18432;
    const u16* ow3p = wp + 22528;

    // load xs (timestep 2*tp)
    for (int idx = tid; idx < 512; idx += 256) {
        int a = idx >> 4, d = idx & 15;
        float v = inputs[(((b * 32 + a) * 64) + 2 * tp) * 16 + d];
        xsf[a][d] = v;
        xsb[a][d] = f2bf(v);
    }

    // W2 B-frags in registers (used E_pad/16 times per step)
    bf16x8 w2f[2][2][4];
#pragma unroll
    for (int k = 0; k < 2; ++k)
#pragma unroll
        for (int s = 0; s < 2; ++s)
#pragma unroll
            for (int t = 0; t < 4; ++t)
                w2f[k][s][t] = *(const bf16x8*)(w2p + (((k * 2 + s) * 4 + t) * 64 + lane) * 8);

    float b1r[2][4], b2r[2][4], o1r[4], o2r[4];
#pragma unroll
    for (int k = 0; k < 2; ++k)
#pragma unroll
        for (int t = 0; t < 4; ++t) {
            b1r[k][t] = mb1[k * 64 + 16 * t + lr];
            b2r[k][t] = mb2[k * 64 + 16 * t + lr];
        }
#pragma unroll
    for (int t = 0; t < 4; ++t) { o1r[t] = ob1[16 * t + lr]; o2r[t] = ob2[16 * t + lr]; }
    const float o3r = ob3[lr];

    __syncthreads();

    for (int step = 0; step < 2; ++step) {
        for (int idx = tid; idx < 2048; idx += 256) ((float*)agg)[idx] = 0.f;
        __syncthreads();

        // ----- edge phase: wave w owns M-tiles [16w,16w+16) (receivers 8w..8w+7)
        for (int m = 16 * w; m < 16 * w + 16; ++m) {
            const int e0 = m * 16;
            const int er = e0 + lr;                   // this lane's A-row edge
            const int ie = er >> 5, je = er & 31;
            const int srow = (g < 2) ? je : ie;       // pre_msg = [send | recv]
            const bf16x8 af = *(const bf16x8*)(&xsb[srow][(g & 1) * 8]);

            float ewv[2][4];
#pragma unroll
            for (int r = 0; r < 4; ++r) {             // D-row r -> edge e0+4g+r
                const float2 wv = *(const float2*)(ew + (e0 + 4 * g + r) * 2);
                ewv[0][r] = wv.x; ewv[1][r] = wv.y;
            }
            const int irecv = e0 >> 5;

#pragma unroll
            for (int k = 0; k < 2; ++k) {
                // layer1: h1 = relu(pre_msg @ W1k + b1k)
                f32x4 c[4];
#pragma unroll
                for (int t = 0; t < 4; ++t) {
                    const bf16x8 bw = *(const bf16x8*)(w1p + ((k * 4 + t) * 64 + lane) * 8);
                    f32x4 z = {0.f, 0.f, 0.f, 0.f};
                    c[t] = __builtin_amdgcn_mfma_f32_16x16x32_bf16(af, bw, z, 0, 0, 0);
                }
#pragma unroll
                for (int t = 0; t < 4; ++t)
#pragma unroll
                    for (int r = 0; r < 4; ++r)
                        slab[w][4 * g + r][16 * t + lr] = f2bf(fmaxf(c[t][r] + b1r[k][t], 0.f));

                // layer2: h2 = relu(h1 @ W2k + b2k); agg[recv] += h2 * ew[e][k]
                const bf16x8 h0 = *(const bf16x8*)(&slab[w][lr][8 * g]);
                const bf16x8 h1 = *(const bf16x8*)(&slab[w][lr][32 + 8 * g]);
#pragma unroll
                for (int t = 0; t < 4; ++t) {
                    f32x4 z = {0.f, 0.f, 0.f, 0.f};
                    f32x4 d = __builtin_amdgcn_mfma_f32_16x16x32_bf16(h0, w2f[k][0][t], z, 0, 0, 0);
                    d = __builtin_amdgcn_mfma_f32_16x16x32_bf16(h1, w2f[k][1][t], d, 0, 0, 0);
                    float sacc = 0.f;
#pragma unroll
                    for (int r = 0; r < 4; ++r)
                        sacc += fmaxf(d[r] + b2r[k][t], 0.f) * ewv[k][r];
                    sacc += __shfl_xor(sacc, 16);
                    sacc += __shfl_xor(sacc, 32);
                    if (g == 0) atomicAdd(&agg[irecv][16 * t + lr], sacc);
                }
            }
        }
        __syncthreads();

        // ----- build aug = [xs | agg | 0pad] in bf16
        for (int idx = tid; idx < 512; idx += 256) augb[idx >> 4][idx & 15] = xsb[idx >> 4][idx & 15];
        for (int idx = tid; idx < 2048; idx += 256) augb[idx >> 6][16 + (idx & 63)] = f2bf(agg[idx >> 6][idx & 63]);
        for (int idx = tid; idx < 512; idx += 256) augb[idx >> 4][80 + (idx & 15)] = 0;
        __syncthreads();

        // ----- out layer 1 (80->64): wave w = N-tile w
        {
            f32x4 c0 = {0.f,0.f,0.f,0.f}, c1 = {0.f,0.f,0.f,0.f};
#pragma unroll
            for (int s = 0; s < 3; ++s) {
                const bf16x8 a0 = *(const bf16x8*)(&augb[lr][32 * s + 8 * g]);
                const bf16x8 a1 = *(const bf16x8*)(&augb[16 + lr][32 * s + 8 * g]);
                const bf16x8 bw = *(const bf16x8*)(ow1p + ((s * 4 + w) * 64 + lane) * 8);
                c0 = __builtin_amdgcn_mfma_f32_16x16x32_bf16(a0, bw, c0, 0, 0, 0);
                c1 = __builtin_amdgcn_mfma_f32_16x16x32_bf16(a1, bw, c1, 0, 0, 0);
            }
#pragma unroll
            for (int r = 0; r < 4; ++r) {
                p1b[4 * g + r][16 * w + lr]      = f2bf(fmaxf(c0[r] + o1r[w], 0.f));
                p1b[16 + 4 * g + r][16 * w + lr] = f2bf(fmaxf(c1[r] + o1r[w], 0.f));
            }
        }
        __syncthreads();

        // ----- out layer 2 (64->64)
        {
            f32x4 c0 = {0.f,0.f,0.f,0.f}, c1 = {0.f,0.f,0.f,0.f};
#pragma unroll
            for (int s = 0; s < 2; ++s) {
                const bf16x8 a0 = *(const bf16x8*)(&p1b[lr][32 * s + 8 * g]);
                const bf16x8 a1 = *(const bf16x8*)(&p1b[16 + lr][32 * s + 8 * g]);
                const bf16x8 bw = *(const bf16x8*)(ow2p + ((s * 4 + w) * 64 + lane) * 8);
                c0 = __builtin_amdgcn_mfma_f32_16x16x32_bf16(a0, bw, c0, 0, 0, 0);
                c1 = __builtin_amdgcn_mfma_f32_16x16x32_bf16(a1, bw, c1, 0, 0, 0);
            }
#pragma unroll
            for (int r = 0; r < 4; ++r) {
                p2b[4 * g + r][16 * w + lr]      = f2bf(fmaxf(c0[r] + o2r[w], 0.f));
                p2b[16 + 4 * g + r][16 * w + lr] = f2bf(fmaxf(c1[r] + o2r[w], 0.f));
            }
        }
        __syncthreads();

        // ----- out layer 3 (64->16) + residual + store; waves 0,1 = M-tiles
        if (w < 2) {
            f32x4 c = {0.f,0.f,0.f,0.f};
#pragma unroll
            for (int s = 0; s < 2; ++s) {
                const bf16x8 a0 = *(const bf16x8*)(&p2b[16 * w + lr][32 * s + 8 * g]);
                const bf16x8 bw = *(const bf16x8*)(ow3p + (s * 64 + lane) * 8);
                c = __builtin_amdgcn_mfma_f32_16x16x32_bf16(a0, bw, c, 0, 0, 0);
            }
            const int tt = 2 * tp + step;
#pragma unroll
            for (int r = 0; r < 4; ++r) {
                const int aa = 16 * w + 4 * g + r;
                const float nv = xsf[aa][lr] + c[r] + o3r;
                xsf[aa][lr] = nv;
                xsb[aa][lr] = f2bf(nv);
                if (tt < 63) out[(((b * 32 + aa) * 63) + tt) * 16 + lr] = nv;
            }
        }
        __syncthreads();
    }
}

extern "C" void kernel_launch(void* const* d_in, const int* in_sizes, int n_in,
                              void* d_out, int out_size, void* d_ws, size_t ws_size,
                              hipStream_t stream) {
    const float* inputs = (const float*)d_in[0];
    const float* rg     = (const float*)d_in[3];
    const float* gb     = (const float*)d_in[4];
    const float* W1     = (const float*)d_in[5];
    const float* mb1    = (const float*)d_in[6];
    const float* W2     = (const float*)d_in[7];
    const float* mb2    = (const float*)d_in[8];
    const float* OW1    = (const float*)d_in[9];
    const float* ob1    = (const float*)d_in[10];
    const float* OW2    = (const float*)d_in[11];
    const float* ob2    = (const float*)d_in[12];
    const float* OW3    = (const float*)d_in[13];
    const float* ob3    = (const float*)d_in[14];

    float* ew = (float*)d_ws;                       // 1024*2 f32 = 8 KiB
    u16*   wpk = (u16*)((char*)d_ws + 8192);        // 23552 u16 ~= 46 KiB

    edge_softmax_k<<<4, 256, 0, stream>>>(rg, gb, ew);
    pack_weights_k<<<92, 256, 0, stream>>>(W1, W2, OW1, OW2, OW3, wpk);
    nri_decoder_k<<<1024, 256, 0, stream>>>(inputs, mb1, mb2, ob1, ob2, ob3,
                                            ew, wpk, (float*)d_out);
}

// Round 2
// 84.462 us; speedup vs baseline: 2.0819x; 2.0819x over previous
//
#include <hip/hip_runtime.h>

typedef unsigned short u16;
typedef unsigned int u32;
typedef __attribute__((ext_vector_type(8))) short bf16x8;
typedef __attribute__((ext_vector_type(4))) float f32x4;
typedef __attribute__((ext_vector_type(4))) u32 u32x4;

__device__ __forceinline__ u32 cvtpk(float lo, float hi) {
    u32 r; asm("v_cvt_pk_bf16_f32 %0, %1, %2" : "=v"(r) : "v"(lo), "v"(hi)); return r;
}
__device__ __forceinline__ u16 f2bf1(float f) { return (u16)(cvtpk(f, f) & 0xffffu); }

__device__ __forceinline__ u16 f2bf(float f) {   // setup kernels only
    union { float f; unsigned u; } v; v.f = f;
    unsigned r = (v.u + 0x7FFFu + ((v.u >> 16) & 1u)) >> 16;
    return (u16)r;
}

// ---------------- setup kernel 1: edge softmax into ws (padded 32x32 grid) ---
__global__ void edge_softmax_k(const float* __restrict__ rg,
                               const float* __restrict__ gb,
                               float* __restrict__ ew) {
    int tid = blockIdx.x * 256 + threadIdx.x;      // 0..1023 = i*32+j
    if (tid >= 1024) return;
    int i = tid >> 5, j = tid & 31;
    float w0 = 0.f, w1 = 0.f;
    if (i != j) {
        int e = i * 31 + j - (j > i ? 1 : 0);      // original edge index
        float a0 = (rg[e * 2 + 0] + gb[e * 2 + 0]) * 2.0f;   // /TAU, TAU=0.5
        float a1 = (rg[e * 2 + 1] + gb[e * 2 + 1]) * 2.0f;
        float m = fmaxf(a0, a1);
        float e0 = expf(a0 - m), e1 = expf(a1 - m);
        float s = e0 + e1;
        w0 = e0 / s; w1 = e1 / s;
    }
    ew[tid * 2 + 0] = w0;
    ew[tid * 2 + 1] = w1;
}

// ---------------- setup kernel 2: pack weights into MFMA fragment order ------
// B-frag (16x16x32): lane l supplies B[32*s + 8*(l>>4) + j][16*t + (l&15)]
// w1tp: A-frag of W1^T with output-col permutation pi(t,a,b)=32(t>>1)+8a+4(t&1)+b
//       lane l, elem j: W1[k][8*(l>>4)+j][pi(t, (l&15)>>2, l&3)]
__global__ void pack_weights_k(const float* __restrict__ W1,   // (2,32,64)
                               const float* __restrict__ W2,   // (2,64,64)
                               const float* __restrict__ OW1,  // (80,64)
                               const float* __restrict__ OW2,  // (64,64)
                               const float* __restrict__ OW3,  // (64,16)
                               u16* __restrict__ wp) {
    int tid = blockIdx.x * 256 + threadIdx.x;
    if (tid < 4096) {                                     // w1tp [k][t][lane][8]
        int j = tid & 7, l = (tid >> 3) & 63, t = (tid >> 9) & 3, k = tid >> 11;
        int kk = 8 * (l >> 4) + j;
        int n  = 32 * (t >> 1) + 8 * ((l & 15) >> 2) + 4 * (t & 1) + (l & 3);
        wp[tid] = f2bf(W1[k * 2048 + kk * 64 + n]);
    } else if (tid < 12288) {                             // w2p [k][s][t][lane][8]
        int x = tid - 4096;
        int j = x & 7, l = (x >> 3) & 63, t = (x >> 9) & 3, s = (x >> 11) & 1, k = x >> 12;
        int kk = 32 * s + 8 * (l >> 4) + j, n = 16 * t + (l & 15);
        wp[tid] = f2bf(W2[k * 4096 + kk * 64 + n]);
    } else if (tid < 18432) {                             // ow1p [s3][t][lane][8], K=80 pad 96
        int x = tid - 12288;
        int j = x & 7, l = (x >> 3) & 63, t = (x >> 9) & 3, s = x >> 11;
        int kk = 32 * s + 8 * (l >> 4) + j, n = 16 * t + (l & 15);
        wp[tid] = f2bf(kk < 80 ? OW1[kk * 64 + n] : 0.f);
    } else if (tid < 22528) {                             // ow2p [s2][t][lane][8]
        int x = tid - 18432;
        int j = x & 7, l = (x >> 3) & 63, t = (x >> 9) & 3, s = x >> 11;
        int kk = 32 * s + 8 * (l >> 4) + j, n = 16 * t + (l & 15);
        wp[tid] = f2bf(OW2[kk * 64 + n]);
    } else if (tid < 23552) {                             // ow3p [s2][lane][8], N=16
        int x = tid - 22528;
        int j = x & 7, l = (x >> 3) & 63, s = x >> 9;
        int kk = 32 * s + 8 * (l >> 4) + j, n = (l & 15);
        wp[tid] = f2bf(OW3[kk * 16 + n]);
    }
}

// ---------------- main fused kernel: one block per (b, tp) -------------------
__global__ __launch_bounds__(256, 2) void nri_decoder_k(
    const float* __restrict__ inputs,   // (32,32,64,16)
    const float* __restrict__ mb1, const float* __restrict__ mb2,
    const float* __restrict__ ob1, const float* __restrict__ ob2,
    const float* __restrict__ ob3,
    const float* __restrict__ ew,       // (1024,2) padded edge weights
    const u16*  __restrict__ wp,        // packed weights
    float* __restrict__ out)            // (32,32,63,16)
{
    __shared__ float xsf[32][16];
    __shared__ __align__(16) u16 xsb[32][24];       // 48B rows
    __shared__ __align__(16) float agg2[2][32][68]; // per-k partial agg, 272B rows
    __shared__ __align__(16) u16 augb[32][104];     // [xs16|agg64|pad16], 208B rows
    __shared__ __align__(16) u16 p1b[32][72];
    __shared__ __align__(16) u16 p2b[32][72];

    const int tid = threadIdx.x;
    const int w = tid >> 6, lane = tid & 63, g = lane >> 4, lr = lane & 15;
    const int kw = w >> 1, w01 = w & 1;             // wave's k-component / receiver half
    const int b = blockIdx.x >> 5, tp = blockIdx.x & 31;

    const u16* w1tp = wp;
    const u16* w2p  = wp + 4096;
    const u16* ow1p = wp + 12288;
    const u16* ow2p = wp + 18432;
    const u16* ow3p = wp + 22528;

    // load xs (timestep 2*tp); init augb xs-part and zero pad
    for (int idx = tid; idx < 512; idx += 256) {
        int a = idx >> 4, d = idx & 15;
        float v = inputs[(((b * 32 + a) * 64) + 2 * tp) * 16 + d];
        u16 bv = f2bf1(v);
        xsf[a][d] = v;
        xsb[a][d] = bv;
        augb[a][d] = bv;
        augb[a][80 + d] = 0;
    }

    // per-wave persistent fragments (k = kw only)
    bf16x8 w1t[4], w2f[2][4];
#pragma unroll
    for (int t = 0; t < 4; ++t)
        w1t[t] = *(const bf16x8*)(w1tp + ((kw * 4 + t) * 64 + lane) * 8);
#pragma unroll
    for (int s = 0; s < 2; ++s)
#pragma unroll
        for (int t = 0; t < 4; ++t)
            w2f[s][t] = *(const bf16x8*)(w2p + (((kw * 2 + s) * 4 + t) * 64 + lane) * 8);

    f32x4 b1c[4];
    float b2r[4];
#pragma unroll
    for (int t = 0; t < 4; ++t) {
#pragma unroll
        for (int r = 0; r < 4; ++r)
            b1c[t][r] = mb1[kw * 64 + 32 * (t >> 1) + 8 * g + 4 * (t & 1) + r];
        b2r[t] = mb2[kw * 64 + 16 * t + lr];
    }
    float o1r[4], o2r[4];
#pragma unroll
    for (int t = 0; t < 4; ++t) { o1r[t] = ob1[16 * t + lr]; o2r[t] = ob2[16 * t + lr]; }
    const float o3r = ob3[lr];

    __syncthreads();

    for (int step = 0; step < 2; ++step) {
        // ----- edge phase: wave (w01,kw) -> receivers 16*w01..+15, component kw.
        // Layer1 transposed (D1 = h1^T with pi-permuted cols) => D1 regs ARE the
        // layer2 A-frags after relu+pack. No LDS, no shuffles between layers.
        for (int p = 0; p < 16; ++p) {
            const int ir = 16 * w01 + p;
            float racc[4] = {0.f, 0.f, 0.f, 0.f};
#pragma unroll
            for (int half = 0; half < 2; ++half) {
                const int m = 2 * ir + half;
                const int e0 = m * 16;
                const int srow = (g < 2) ? (16 * (m & 1) + lr) : (m >> 1);
                const bf16x8 bfrag = *(const bf16x8*)(&xsb[srow][(g & 1) * 8]);

                float ewv[4];
#pragma unroll
                for (int r = 0; r < 4; ++r) ewv[r] = ew[(e0 + 4 * g + r) * 2 + kw];

                // layer1 (K=32, bias via C-init): c[t][r] = h1pre[e0+lr][pi(t,g,r)]
                f32x4 c0 = __builtin_amdgcn_mfma_f32_16x16x32_bf16(w1t[0], bfrag, b1c[0], 0, 0, 0);
                f32x4 c1 = __builtin_amdgcn_mfma_f32_16x16x32_bf16(w1t[1], bfrag, b1c[1], 0, 0, 0);
                f32x4 c2 = __builtin_amdgcn_mfma_f32_16x16x32_bf16(w1t[2], bfrag, b1c[2], 0, 0, 0);
                f32x4 c3 = __builtin_amdgcn_mfma_f32_16x16x32_bf16(w1t[3], bfrag, b1c[3], 0, 0, 0);

                // relu + pack: pk in t-order = the two layer2 A-frags
                union { u32 u[8]; bf16x8 v[2]; } a2;
                a2.u[0] = cvtpk(fmaxf(c0[0], 0.f), fmaxf(c0[1], 0.f));
                a2.u[1] = cvtpk(fmaxf(c0[2], 0.f), fmaxf(c0[3], 0.f));
                a2.u[2] = cvtpk(fmaxf(c1[0], 0.f), fmaxf(c1[1], 0.f));
                a2.u[3] = cvtpk(fmaxf(c1[2], 0.f), fmaxf(c1[3], 0.f));
                a2.u[4] = cvtpk(fmaxf(c2[0], 0.f), fmaxf(c2[1], 0.f));
                a2.u[5] = cvtpk(fmaxf(c2[2], 0.f), fmaxf(c2[3], 0.f));
                a2.u[6] = cvtpk(fmaxf(c3[0], 0.f), fmaxf(c3[1], 0.f));
                a2.u[7] = cvtpk(fmaxf(c3[2], 0.f), fmaxf(c3[3], 0.f));

                // layer2 (K=64, bias via C-init); accumulate weighted edge sum
#pragma unroll
                for (int t = 0; t < 4; ++t) {
                    f32x4 d = {b2r[t], b2r[t], b2r[t], b2r[t]};
                    d = __builtin_amdgcn_mfma_f32_16x16x32_bf16(a2.v[0], w2f[0][t], d, 0, 0, 0);
                    d = __builtin_amdgcn_mfma_f32_16x16x32_bf16(a2.v[1], w2f[1][t], d, 0, 0, 0);
#pragma unroll
                    for (int r = 0; r < 4; ++r)
                        racc[t] += fmaxf(d[r], 0.f) * ewv[r];
                }
            }
            // reduce over g (16 edges done: 4 in-lane + cross-g butterfly)
#pragma unroll
            for (int t = 0; t < 4; ++t) {
                racc[t] += __shfl_xor(racc[t], 16);
                racc[t] += __shfl_xor(racc[t], 32);
            }
            float v = (g & 2) ? ((g & 1) ? racc[3] : racc[2])
                              : ((g & 1) ? racc[1] : racc[0]);
            agg2[kw][ir][16 * g + lr] = v;
        }
        __syncthreads();

        // ----- augb agg-part: sum the two k-planes, convert to bf16
        {
            const int a = tid >> 3, cc = (tid & 7) * 8;
            f32x4 x0 = *(const f32x4*)&agg2[0][a][cc];
            f32x4 x1 = *(const f32x4*)&agg2[0][a][cc + 4];
            f32x4 y0 = *(const f32x4*)&agg2[1][a][cc];
            f32x4 y1 = *(const f32x4*)&agg2[1][a][cc + 4];
            x0 += y0; x1 += y1;
            u32x4 q = { cvtpk(x0[0], x0[1]), cvtpk(x0[2], x0[3]),
                        cvtpk(x1[0], x1[1]), cvtpk(x1[2], x1[3]) };
            *(u32x4*)&augb[a][16 + cc] = q;
        }
        __syncthreads();

        // ----- out layer 1 (80->64): wave w = N-tile w
        {
            f32x4 c0 = {o1r[w], o1r[w], o1r[w], o1r[w]};
            f32x4 c1 = c0;
#pragma unroll
            for (int s = 0; s < 3; ++s) {
                const bf16x8 a0 = *(const bf16x8*)(&augb[lr][32 * s + 8 * g]);
                const bf16x8 a1 = *(const bf16x8*)(&augb[16 + lr][32 * s + 8 * g]);
                const bf16x8 bw = *(const bf16x8*)(ow1p + ((s * 4 + w) * 64 + lane) * 8);
                c0 = __builtin_amdgcn_mfma_f32_16x16x32_bf16(a0, bw, c0, 0, 0, 0);
                c1 = __builtin_amdgcn_mfma_f32_16x16x32_bf16(a1, bw, c1, 0, 0, 0);
            }
#pragma unroll
            for (int r = 0; r < 4; ++r) {
                p1b[4 * g + r][16 * w + lr]      = f2bf1(fmaxf(c0[r], 0.f));
                p1b[16 + 4 * g + r][16 * w + lr] = f2bf1(fmaxf(c1[r], 0.f));
            }
        }
        __syncthreads();

        // ----- out layer 2 (64->64)
        {
            f32x4 c0 = {o2r[w], o2r[w], o2r[w], o2r[w]};
            f32x4 c1 = c0;
#pragma unroll
            for (int s = 0; s < 2; ++s) {
                const bf16x8 a0 = *(const bf16x8*)(&p1b[lr][32 * s + 8 * g]);
                const bf16x8 a1 = *(const bf16x8*)(&p1b[16 + lr][32 * s + 8 * g]);
                const bf16x8 bw = *(const bf16x8*)(ow2p + ((s * 4 + w) * 64 + lane) * 8);
                c0 = __builtin_amdgcn_mfma_f32_16x16x32_bf16(a0, bw, c0, 0, 0, 0);
                c1 = __builtin_amdgcn_mfma_f32_16x16x32_bf16(a1, bw, c1, 0, 0, 0);
            }
#pragma unroll
            for (int r = 0; r < 4; ++r) {
                p2b[4 * g + r][16 * w + lr]      = f2bf1(fmaxf(c0[r], 0.f));
                p2b[16 + 4 * g + r][16 * w + lr] = f2bf1(fmaxf(c1[r], 0.f));
            }
        }
        __syncthreads();

        // ----- out layer 3 (64->16) + residual + store; waves 0,1 = M-tiles
        if (w < 2) {
            f32x4 c = {o3r, o3r, o3r, o3r};
#pragma unroll
            for (int s = 0; s < 2; ++s) {
                const bf16x8 a0 = *(const bf16x8*)(&p2b[16 * w + lr][32 * s + 8 * g]);
                const bf16x8 bw = *(const bf16x8*)(ow3p + (s * 64 + lane) * 8);
                c = __builtin_amdgcn_mfma_f32_16x16x32_bf16(a0, bw, c, 0, 0, 0);
            }
            const int tt = 2 * tp + step;
#pragma unroll
            for (int r = 0; r < 4; ++r) {
                const int aa = 16 * w + 4 * g + r;
                const float nv = xsf[aa][lr] + c[r];
                u16 bv = f2bf1(nv);
                xsf[aa][lr] = nv;
                xsb[aa][lr] = bv;
                augb[aa][lr] = bv;
                if (tt < 63) out[(((b * 32 + aa) * 63) + tt) * 16 + lr] = nv;
            }
        }
        __syncthreads();
    }
}

extern "C" void kernel_launch(void* const* d_in, const int* in_sizes, int n_in,
                              void* d_out, int out_size, void* d_ws, size_t ws_size,
                              hipStream_t stream) {
    const float* inputs = (const float*)d_in[0];
    const float* rg     = (const float*)d_in[3];
    const float* gb     = (const float*)d_in[4];
    const float* W1     = (const float*)d_in[5];
    const float* mb1    = (const float*)d_in[6];
    const float* W2     = (const float*)d_in[7];
    const float* mb2    = (const float*)d_in[8];
    const float* OW1    = (const float*)d_in[9];
    const float* ob1    = (const float*)d_in[10];
    const float* OW2    = (const float*)d_in[11];
    const float* ob2    = (const float*)d_in[12];
    const float* OW3    = (const float*)d_in[13];
    const float* ob3    = (const float*)d_in[14];

    float* ew = (float*)d_ws;                       // 1024*2 f32 = 8 KiB
    u16*   wpk = (u16*)((char*)d_ws + 8192);        // 23552 u16 ~= 46 KiB

    edge_softmax_k<<<4, 256, 0, stream>>>(rg, gb, ew);
    pack_weights_k<<<92, 256, 0, stream>>>(W1, W2, OW1, OW2, OW3, wpk);
    nri_decoder_k<<<1024, 256, 0, stream>>>(inputs, mb1, mb2, ob1, ob2, ob3,
                                            ew, wpk, (float*)d_out);
}